// Round 1
// baseline (71.150 us; speedup 1.0000x reference)
//
#include <hip/hip_runtime.h>
#include <math.h>

#define RR 16
#define AA 8
#define BLOCK 256

// exp(-0.5*S) with full f64 dynamic range:
//   t = -0.5*log2(e)*S ;  2^t = 2^floor(t) * exp2(frac(t))
__device__ __forceinline__ double dexp_half(float S) {
    float t  = S * -0.72134752044448f;   // -0.5 * log2(e)
    float fl = floorf(t);
    float fr = t - fl;                   // in [0,1)
    float p  = __builtin_amdgcn_exp2f(fr);
    return ldexp((double)p, (int)fl);
}

__global__ __launch_bounds__(BLOCK) void t2fls_kernel(
    const float* __restrict__ x,   // N x 8
    const float* __restrict__ W,   // 384 (uses [0..129])
    const float* __restrict__ c1,  // 16
    const float* __restrict__ c2,  // 16
    float* __restrict__ out,       // N
    int n)
{
    __shared__ float m_s[RR * AA], isb_s[RR * AA], iss_s[RR * AA];
    __shared__ float c1s_s[RR], c2s_s[RR];
    __shared__ int   p1_s[RR], p2_s[RR];
    __shared__ float Sb_s[RR][BLOCK];   // sum d^2 with bigger sigma  -> UU
    __shared__ float Ss_s[RR][BLOCK];   // sum d^2 with smaller sigma -> LL

    const int tid = threadIdx.x;

    // ---- per-block prep (cheap, redundant across blocks; all L2-cached) ----
    if (tid < RR * AA) {
        // offsets[r][a] = 8r+a ; m=W[o], s1=W[o+1], s2=W[o+2] (overlapping by design)
        float m  = W[tid];
        float s1 = W[tid + 1];
        float s2 = W[tid + 2];
        float sbig = fmaxf(s1, s2);     // bigger sigma  -> bigger z -> mu_big
        float ssml = fminf(s1, s2);     // smaller sigma -> smaller z -> mu_small
        m_s[tid]   = m;
        isb_s[tid] = 1.0f / sbig;
        iss_s[tid] = 1.0f / ssml;
    }
    // stable rank-sort of c1 (threads 128..143) and c2 (threads 160..175)
    if (tid >= 128 && tid < 128 + RR) {
        int i = tid - 128;
        float vi = c1[i];
        int rank = 0;
        #pragma unroll
        for (int j = 0; j < RR; ++j) {
            float vj = c1[j];
            rank += (vj < vi) || (vj == vi && j < i);
        }
        c1s_s[rank] = vi;
        p1_s[rank]  = i;
    }
    if (tid >= 160 && tid < 160 + RR) {
        int i = tid - 160;
        float vi = c2[i];
        int rank = 0;
        #pragma unroll
        for (int j = 0; j < RR; ++j) {
            float vj = c2[j];
            rank += (vj < vi) || (vj == vi && j < i);
        }
        c2s_s[rank] = vi;
        p2_s[rank]  = i;
    }
    __syncthreads();

    const int gid = blockIdx.x * BLOCK + tid;
    if (gid >= n) return;   // no barriers past this point

    // ---- firing strengths: S sums per rule ----
    const float4* xp = (const float4*)(x + (size_t)gid * AA);
    float4 xlo = xp[0], xhi = xp[1];
    float xv[AA] = {xlo.x, xlo.y, xlo.z, xlo.w, xhi.x, xhi.y, xhi.z, xhi.w};

    #pragma unroll
    for (int r = 0; r < RR; ++r) {
        float sb = 0.0f, ss = 0.0f;
        #pragma unroll
        for (int a = 0; a < AA; ++a) {
            const int c = r * AA + a;
            float t  = xv[a] - m_s[c];
            float db = t * isb_s[c];
            float ds = t * iss_s[c];
            sb = fmaf(db, db, sb);
            ss = fmaf(ds, ds, ss);
        }
        Sb_s[r][tid] = sb;   // own column only; no barrier needed
        Ss_s[r][tid] = ss;
    }

    // ---- LEFT endpoint (KM descent on c1-sorted order) ----
    double s0 = 0.0, t0 = 0.0;
    #pragma unroll
    for (int k = 0; k < RR; ++k) {
        int p = p1_s[k];
        double l = dexp_half(Ss_s[p][tid]);
        s0 = fma((double)c1s_s[k], l, s0);
        t0 += l;
    }
    double bn = s0, bd = t0;        // best ratio as fraction bn/bd
    double cs = s0, ct = t0;        // running (s0+cumsum), (t0+cumsum)
    #pragma unroll
    for (int k = 0; k < RR; ++k) {
        int p = p1_s[k];
        double u  = dexp_half(Sb_s[p][tid]);
        double l  = dexp_half(Ss_s[p][tid]);
        double dd = u - l;          // >= 0
        cs = fma((double)c1s_s[k], dd, cs);
        ct += dd;
        // cs/ct < bn/bd  <=>  cs*bd < bn*ct   (denominators > 0)
        if (cs * bd < bn * ct) { bn = cs; bd = ct; }
    }
    double left = bn / bd;

    // ---- RIGHT endpoint (KM ascent on c2-sorted order) ----
    double s0r = 0.0, t0r = 0.0;
    #pragma unroll
    for (int k = 0; k < RR; ++k) {
        int p = p2_s[k];
        double u = dexp_half(Sb_s[p][tid]);
        s0r = fma((double)c2s_s[k], u, s0r);
        t0r += u;
    }
    bn = s0r; bd = t0r;
    cs = s0r; ct = t0r;
    #pragma unroll
    for (int k = 0; k < RR; ++k) {
        int p = p2_s[k];
        double u  = dexp_half(Sb_s[p][tid]);
        double l  = dexp_half(Ss_s[p][tid]);
        double dd = l - u;          // <= 0
        cs = fma((double)c2s_s[k], dd, cs);
        ct += dd;
        if (cs * bd > bn * ct) { bn = cs; bd = ct; }
    }
    double right = bn / bd;

    out[gid] = (float)(0.5 * (left + right));
}

extern "C" void kernel_launch(void* const* d_in, const int* in_sizes, int n_in,
                              void* d_out, int out_size, void* d_ws, size_t ws_size,
                              hipStream_t stream) {
    const float* x  = (const float*)d_in[0];
    const float* W  = (const float*)d_in[1];
    const float* c1 = (const float*)d_in[2];
    const float* c2 = (const float*)d_in[3];
    float* out = (float*)d_out;
    const int n = out_size;            // 262144
    const int blocks = (n + BLOCK - 1) / BLOCK;
    hipLaunchKernelGGL(t2fls_kernel, dim3(blocks), dim3(BLOCK), 0, stream,
                       x, W, c1, c2, out, n);
}

// Round 2
// 69.958 us; speedup vs baseline: 1.0170x; 1.0170x over previous
//
#include <hip/hip_runtime.h>
#include <math.h>

#define RR 16
#define AA 8
#define BLOCK 256

// ws float layout:
//   [0..127]    m
//   [128..255]  1/sigma_big   (bigger sigma  -> mu_big / UU)
//   [256..383]  1/sigma_small (smaller sigma -> mu_small / LL)
//   [384..399]  c1 sorted
//   [400..415]  p1 perm (int)
//   [416..431]  c2 sorted
//   [432..447]  p2 perm (int)

__global__ void prep_kernel(const float* __restrict__ W,
                            const float* __restrict__ c1,
                            const float* __restrict__ c2,
                            float* __restrict__ ws) {
    int t = threadIdx.x;   // 128 threads, 1 block
    if (t < RR * AA) {
        float m  = W[t];
        float s1 = W[t + 1];
        float s2 = W[t + 2];
        ws[t]        = m;
        ws[128 + t]  = 1.0f / fmaxf(s1, s2);
        ws[256 + t]  = 1.0f / fminf(s1, s2);
    }
    if (t < RR) {
        // stable rank-sort (matches jnp.argsort)
        float vi = c1[t];
        int rank = 0;
        #pragma unroll
        for (int j = 0; j < RR; ++j) {
            float vj = c1[j];
            rank += (vj < vi) || (vj == vi && j < t);
        }
        ws[384 + rank] = vi;
        ((int*)ws)[400 + rank] = t;

        float wi = c2[t];
        rank = 0;
        #pragma unroll
        for (int j = 0; j < RR; ++j) {
            float vj = c2[j];
            rank += (vj < wi) || (vj == wi && j < t);
        }
        ws[416 + rank] = wi;
        ((int*)ws)[432 + rank] = t;
    }
}

__global__ __launch_bounds__(BLOCK) void t2fls_main(
    const float* __restrict__ x,    // N x 8
    const float* __restrict__ c1,   // 16 (unsorted ok for s0 sums)
    const float* __restrict__ c2,   // 16
    const float* __restrict__ ws,   // prepped uniforms (scalarizable)
    float* __restrict__ out,        // N
    int n)
{
    __shared__ float2 UL[RR][BLOCK];   // 32 KiB; column-per-thread, no barrier needed

    const int tid = threadIdx.x;
    const int gid = blockIdx.x * BLOCK + tid;
    if (gid >= n) return;

    const float4* xp = (const float4*)(x + (size_t)gid * AA);
    float4 a0 = xp[0], a1 = xp[1];
    float xv[AA] = {a0.x, a0.y, a0.z, a0.w, a1.x, a1.y, a1.z, a1.w};

    const float* pm = ws;
    const float* pb = ws + 128;
    const float* ps = ws + 256;

    // ---- firing: per-rule sums of d^2 (f32, static register arrays) ----
    float sb[RR], ss[RR];
    #pragma unroll
    for (int r = 0; r < RR; ++r) {
        float accb = 0.0f, accs = 0.0f;
        #pragma unroll
        for (int a = 0; a < AA; ++a) {
            const int c = r * AA + a;
            float t  = xv[a] - pm[c];     // pm[c]: uniform -> SGPR
            float db = t * pb[c];
            float ds = t * ps[c];
            accb = fmaf(db, db, accb);
            accs = fmaf(ds, ds, accs);
        }
        sb[r] = accb;
        ss[r] = accs;
    }

    // ---- relative rescale: weights scaled by 2^(0.72*Smin) (exact pow2) ----
    float smin = sb[0];
    #pragma unroll
    for (int r = 1; r < RR; ++r) smin = fminf(smin, sb[r]);

    const float K = 0.72134752044448f;   // 0.5 * log2(e)

    float s0 = 0.0f, t0 = 0.0f, s0r = 0.0f, t0r = 0.0f;
    #pragma unroll
    for (int r = 0; r < RR; ++r) {
        float u = __builtin_amdgcn_exp2f((smin - sb[r]) * K);  // scaled UU, max = 1
        float l = __builtin_amdgcn_exp2f((smin - ss[r]) * K);  // scaled LL, l <= u
        UL[r][tid] = make_float2(u, l);
        float cc1 = c1[r];   // uniform -> SGPR
        float cc2 = c2[r];
        s0  = fmaf(cc1, l, s0);   t0  += l;   // order-independent sums
        s0r = fmaf(cc2, u, s0r);  t0r += u;
    }

    const float* c1s = ws + 384;
    const int*   p1  = (const int*)ws + 400;
    const float* c2s = ws + 416;
    const int*   p2  = (const int*)ws + 432;

    // ---- LEFT endpoint: prefix-min of ratios in c1-sorted order ----
    float bn = s0, bd = t0, cs = s0, ct = t0;
    #pragma unroll
    for (int k = 0; k < RR; ++k) {
        int p = p1[k];                     // uniform -> SGPR
        float2 ul = UL[p][tid];
        float dd = ul.x - ul.y;            // u - l >= 0
        cs = fmaf(c1s[k], dd, cs);
        ct += dd;
        // cs/ct < bn/bd  <=>  cs*bd < bn*ct  (denominators > 0)
        bool bet = (cs * bd < bn * ct);
        bn = bet ? cs : bn;
        bd = bet ? ct : bd;
    }
    float left = bn / bd;

    // ---- RIGHT endpoint: prefix-max in c2-sorted order ----
    bn = s0r; bd = t0r; cs = s0r; ct = t0r;
    #pragma unroll
    for (int k = 0; k < RR; ++k) {
        int p = p2[k];
        float2 ul = UL[p][tid];
        float dd = ul.y - ul.x;            // l - u <= 0
        cs = fmaf(c2s[k], dd, cs);
        ct += dd;
        bool bet = (cs * bd > bn * ct);
        bn = bet ? cs : bn;
        bd = bet ? ct : bd;
    }
    float right = bn / bd;

    out[gid] = 0.5f * (left + right);
}

extern "C" void kernel_launch(void* const* d_in, const int* in_sizes, int n_in,
                              void* d_out, int out_size, void* d_ws, size_t ws_size,
                              hipStream_t stream) {
    const float* x  = (const float*)d_in[0];
    const float* W  = (const float*)d_in[1];
    const float* c1 = (const float*)d_in[2];
    const float* c2 = (const float*)d_in[3];
    float* out = (float*)d_out;
    float* ws  = (float*)d_ws;
    const int n = out_size;   // 262144

    hipLaunchKernelGGL(prep_kernel, dim3(1), dim3(128), 0, stream, W, c1, c2, ws);

    const int blocks = (n + BLOCK - 1) / BLOCK;
    hipLaunchKernelGGL(t2fls_main, dim3(blocks), dim3(BLOCK), 0, stream,
                       x, c1, c2, ws, out, n);
}